// Round 8
// baseline (429.560 us; speedup 1.0000x reference)
//
#include <hip/hip_runtime.h>
#include <hip/hip_bf16.h>
#include <cstddef>

#define GLOBAL_AS __attribute__((address_space(1)))
#define LDS_AS __attribute__((address_space(3)))

typedef __bf16 bf16_t;
typedef __bf16 bf16x8 __attribute__((ext_vector_type(8)));
typedef __bf16 bf16x4 __attribute__((ext_vector_type(4)));
typedef float f32x4 __attribute__((ext_vector_type(4)));

static constexpr int Tseq  = 4096;
static constexpr int Dd    = 1024;
static constexpr int Mrows = 8 * 4096;            // 32768
static constexpr int UGRP  = 8388608;             // u float4-groups (32M/4)

// ---------------- fused cast: u -> u16, (WB,WBf) -> wcat --------------------
__global__ __launch_bounds__(256) void k_prep(const float* __restrict__ u,
                                              const float* __restrict__ WB,
                                              const float* __restrict__ WBf,
                                              bf16_t* __restrict__ u16,
                                              bf16_t* __restrict__ wcat) {
    const int i = blockIdx.x * 256 + threadIdx.x;
    if (i < UGRP) {
        float4 v = reinterpret_cast<const float4*>(u)[i];
        bf16x4 o;
        o[0] = (__bf16)v.x; o[1] = (__bf16)v.y; o[2] = (__bf16)v.z; o[3] = (__bf16)v.w;
        reinterpret_cast<bf16x4*>(u16)[i] = o;
    } else {
        const int j  = i - UGRP;                  // 0 .. 524287
        const int e4 = j * 4;
        const float* s = (e4 < 1024 * 1024) ? (WB + e4) : (WBf + (e4 - 1024 * 1024));
        float4 v = *reinterpret_cast<const float4*>(s);
        bf16x4 o;
        o[0] = (__bf16)v.x; o[1] = (__bf16)v.y; o[2] = (__bf16)v.z; o[3] = (__bf16)v.w;
        reinterpret_cast<bf16x4*>(wcat)[j] = o;
    }
}

// ---------------- 256x256x64 pipelined GEMM, 2 phases per K-tile -------------
// C[m,n] = sum_k A[m,k]*Bt[n,k]; M=32768, N=2048, K=1024.
// 512 thr = 8 waves (4 Mq x 2 Nq); per-wave 64x128 out.
// Phase A: RD A0,A1,B0 | stage A0',B0',A1' | bar | 32 MFMA | vmcnt(6) | bar
// Phase B: RD B1       | stage B1'         | bar | 32 MFMA | vmcnt(2) | bar
// LDS 128 KiB: [buf2][A|B][half2][128 rows][128 B], XOR-swizzle (row&7)<<4.
__global__ __launch_bounds__(512, 2) void k_gemm(const bf16_t* __restrict__ A,
                                                 const bf16_t* __restrict__ Bt,
                                                 bf16_t* __restrict__ xf,
                                                 bf16_t* __restrict__ xb) {
    __shared__ __align__(16) char sm[131072];

    const int tid  = threadIdx.x;
    const int wid  = tid >> 6;
    const int lane = tid & 63;
    const int lane15 = lane & 15;
    const int g16  = (lane >> 4) * 16;     // byte offset from k-group
    const int wmq  = wid >> 1;             // 0..3
    const int wnq  = wid & 1;              // 0..1

    // bijective XCD swizzle (nwg=1024, 8 XCDs)
    const int bid0 = blockIdx.x;
    const int swzb = (bid0 & 7) * 128 + (bid0 >> 3);
    const int bcol = swzb & 7;             // 8 col tiles of 256 over Ncat=2048
    const int brow = swzb >> 3;            // 128 row tiles of 256

    // staging source: dest byte L = tid*16 (+8192); logical = L ^ ((row&7)<<4)
    const int srow = tid >> 3;                        // 0..63
    const int scol = ((tid & 7) ^ (srow & 7)) * 8;    // elems
    const bf16_t* gA = A  + ((size_t)brow * 256 + srow) * 1024 + scol;
    const bf16_t* gB = Bt + ((size_t)bcol * 256 + srow) * 1024 + scol;

    char* const smw = sm + wid * 1024;     // per-wave stage dest (wave-uniform)

    f32x4 acc[2][2][2][4] = {};            // [mh][mi][nh][ni]
    bf16x8 afr[2][2][2];                   // [mh][mi][kk]  (A0,A1 persist)
    bf16x8 bfr[4][2];                      // [ni][kk]

#define STAGE(bufb, isA, h, kt1) do {                                          \
    const bf16_t* _s = ((isA) ? gA : gB) + (size_t)(h) * 131072 + (kt1) * 64;  \
    char* _l = smw + (bufb) * 65536 + ((isA) ? 0 : 32768) + (h) * 16384;       \
    __builtin_amdgcn_global_load_lds((const GLOBAL_AS void*)_s,                \
                                     (LDS_AS void*)_l, 16, 0, 0);              \
    __builtin_amdgcn_global_load_lds((const GLOBAL_AS void*)(_s + 65536),      \
                                     (LDS_AS void*)(_l + 8192), 16, 0, 0);     \
} while (0)

#define RD_A(bufb, mhh) do {                                                   \
    _Pragma("unroll") for (int mi = 0; mi < 2; ++mi) {                         \
      const int rr = wmq * 32 + mi * 16 + lane15;                              \
      const char* _p = sm + (bufb) * 65536 + (mhh) * 16384 + rr * 128;         \
      const int sz = (rr & 7) << 4;                                            \
      _Pragma("unroll") for (int kk = 0; kk < 2; ++kk)                         \
        afr[mhh][mi][kk] = *reinterpret_cast<const bf16x8*>(_p + ((kk * 64 + g16) ^ sz)); \
    } } while (0)

#define RD_B(bufb, nhh) do {                                                   \
    _Pragma("unroll") for (int ni = 0; ni < 4; ++ni) {                         \
      const int rr = wnq * 64 + ni * 16 + lane15;                              \
      const char* _p = sm + (bufb) * 65536 + 32768 + (nhh) * 16384 + rr * 128; \
      const int sz = (rr & 7) << 4;                                            \
      _Pragma("unroll") for (int kk = 0; kk < 2; ++kk)                         \
        bfr[ni][kk] = *reinterpret_cast<const bf16x8*>(_p + ((kk * 64 + g16) ^ sz)); \
    } } while (0)

#define MM(MH, NH) do {                                                        \
    _Pragma("unroll") for (int kk = 0; kk < 2; ++kk)                           \
    _Pragma("unroll") for (int mi = 0; mi < 2; ++mi)                           \
    _Pragma("unroll") for (int ni = 0; ni < 4; ++ni)                           \
      acc[MH][mi][NH][ni] = __builtin_amdgcn_mfma_f32_16x16x32_bf16(           \
          afr[MH][mi][kk], bfr[ni][kk], acc[MH][mi][NH][ni], 0, 0, 0);         \
} while (0)

#define BARM() asm volatile("s_barrier" ::: "memory")

    // prologue: stage all 4 halves of tile 0 (issue order A0,B0,A1,B1)
    STAGE(0, 1, 0, 0);
    STAGE(0, 0, 0, 0);
    STAGE(0, 1, 1, 0);
    STAGE(0, 0, 1, 0);
    asm volatile("s_waitcnt vmcnt(2)" ::: "memory");   // A0,B0,A1 done
    BARM();

#pragma unroll 2
    for (int t = 0; t < 16; ++t) {
        const int buf = t & 1;
        const bool pf = t < 15;
        const int k1 = t + 1;
        // ---- Phase A: A0,A1,B0 reads; stage A0',B0',A1'
        RD_A(buf, 0); RD_A(buf, 1); RD_B(buf, 0);
        if (pf) { STAGE(buf ^ 1, 1, 0, k1); STAGE(buf ^ 1, 0, 0, k1); STAGE(buf ^ 1, 1, 1, k1); }
        __builtin_amdgcn_s_barrier();
        __builtin_amdgcn_s_setprio(1);
        MM(0, 0); MM(1, 0);
        __builtin_amdgcn_s_setprio(0);
        if (pf) { asm volatile("s_waitcnt vmcnt(6)" ::: "memory"); }   // B1(t) done
        else    { asm volatile("s_waitcnt vmcnt(0)" ::: "memory"); }
        BARM();
        // ---- Phase B: B1 reads; stage B1'
        RD_B(buf, 1);
        if (pf) STAGE(buf ^ 1, 0, 1, k1);
        __builtin_amdgcn_s_barrier();
        __builtin_amdgcn_s_setprio(1);
        MM(1, 1); MM(0, 1);
        __builtin_amdgcn_s_setprio(0);
        if (pf) { asm volatile("s_waitcnt vmcnt(2)" ::: "memory"); }   // A0',B0',A1' done
        BARM();
    }

    // C-write. n<1024 -> xf[m,n]; n>=1024 -> xb[m-1,n-1024] (skip m==0).
    const bool isF  = bcol < 4;           // block-uniform
    const int rbase = brow * 256 + wmq * 32 + (lane >> 4) * 4;
    const int cb0   = bcol * 256 + wnq * 64 + lane15;
    #pragma unroll
    for (int mh = 0; mh < 2; ++mh)
    #pragma unroll
    for (int mi = 0; mi < 2; ++mi)
    #pragma unroll
    for (int j = 0; j < 4; ++j) {
        const int r = rbase + mh * 128 + mi * 16 + j;
        #pragma unroll
        for (int nh = 0; nh < 2; ++nh)
        #pragma unroll
        for (int ni = 0; ni < 4; ++ni) {
            const int c = cb0 + nh * 128 + ni * 16;
            const __bf16 v = (__bf16)acc[mh][mi][nh][ni][j];
            if (isF)         xf[(size_t)r * 1024 + c] = v;
            else if (r >= 1) xb[(size_t)(r - 1) * 1024 + (c - 1024)] = v;
        }
    }
#undef STAGE
#undef RD_A
#undef RD_B
#undef MM
#undef BARM
}

// ---------------- epilogue: TWO rows per wave (ILP), bf16 u, float4 weights --
__global__ __launch_bounds__(256) void k_epi(const bf16_t* __restrict__ u16,
                                             const bf16_t* __restrict__ xf,
                                             const bf16_t* __restrict__ xb,
                                             const float* __restrict__ w1,
                                             const float* __restrict__ w2,
                                             const float* __restrict__ bb,
                                             const float* __restrict__ Wc,
                                             float* __restrict__ y,
                                             float* __restrict__ gout,
                                             float* __restrict__ fout) {
    const int lane = threadIdx.x & 63;
    const int r0   = blockIdx.x * 8 + (threadIdx.x >> 6) * 2;   // rows r0, r0+1

    // issue all 12 row loads first
    bf16x8 u8[2][2], f8[2][2], b8[2][2];
    #pragma unroll
    for (int rr = 0; rr < 2; ++rr) {
        const size_t rb = (size_t)(r0 + rr) * Dd;
        #pragma unroll
        for (int j = 0; j < 2; ++j) {
            const int e = j * 512 + lane * 8;
            u8[rr][j] = *reinterpret_cast<const bf16x8*>(u16 + rb + e);
            f8[rr][j] = *reinterpret_cast<const bf16x8*>(xf + rb + e);
            b8[rr][j] = *reinterpret_cast<const bf16x8*>(xb + rb + e);
        }
    }
    // weights as float4 (12 loads total)
    float w1v[16], w2v[16], wcv[16];
    #pragma unroll
    for (int j = 0; j < 2; ++j) {
        const int q4 = j * 128 + lane * 2;      // float4 index of e = j*512+lane*8
        #pragma unroll
        for (int h = 0; h < 2; ++h) {
            const float4 a = reinterpret_cast<const float4*>(w1)[q4 + h];
            const float4 c = reinterpret_cast<const float4*>(w2)[q4 + h];
            const float4 w = reinterpret_cast<const float4*>(Wc)[q4 + h];
            const int o = j * 8 + h * 4;
            w1v[o+0] = a.x; w1v[o+1] = a.y; w1v[o+2] = a.z; w1v[o+3] = a.w;
            w2v[o+0] = c.x; w2v[o+1] = c.y; w2v[o+2] = c.z; w2v[o+3] = c.w;
            wcv[o+0] = w.x; wcv[o+1] = w.y; wcv[o+2] = w.z; wcv[o+3] = w.w;
        }
    }

    float uv[2][16], xfv[2][16], xbv[2][16];
    #pragma unroll
    for (int rr = 0; rr < 2; ++rr) {
        const int t = (r0 + rr) & (Tseq - 1);
        #pragma unroll
        for (int j = 0; j < 2; ++j) {
            #pragma unroll
            for (int i = 0; i < 8; ++i) {
                uv[rr][j*8+i]  = (float)u8[rr][j][i];
                xfv[rr][j*8+i] = (float)f8[rr][j][i];
                xbv[rr][j*8+i] = (float)b8[rr][j][i];
            }
        }
        if (t == 0) {
            #pragma unroll
            for (int i = 0; i < 16; ++i) xfv[rr][i] = uv[rr][i];
        }
        if (t == Tseq - 1) {
            #pragma unroll
            for (int i = 0; i < 16; ++i) xbv[rr][i] = uv[rr][i];
        }
    }

    float part[2] = {0.0f, 0.0f};
    #pragma unroll
    for (int rr = 0; rr < 2; ++rr)
        #pragma unroll
        for (int i = 0; i < 16; ++i)
            part[rr] += xfv[rr][i] * w1v[i] + xbv[rr][i] * w2v[i];
    #pragma unroll
    for (int off = 32; off >= 1; off >>= 1) {
        part[0] += __shfl_xor(part[0], off);
        part[1] += __shfl_xor(part[1], off);
    }
    const float bias = bb[0];
    float g[2];
    g[0] = 1.0f / (1.0f + __expf(-(part[0] + bias)));
    g[1] = 1.0f / (1.0f + __expf(-(part[1] + bias)));

    float p2[2] = {0.0f, 0.0f};
    #pragma unroll
    for (int rr = 0; rr < 2; ++rr) {
        const size_t rb = (size_t)(r0 + rr) * Dd;
        #pragma unroll
        for (int j = 0; j < 4; ++j) {          // 4 x float4 stores per row
            float4 yv;
            const int e = (j >> 1) * 512 + lane * 8 + (j & 1) * 4;
            const int q = (j >> 1) * 8 + (j & 1) * 4;
            yv.x = g[rr] * (xfv[rr][q+0] + xbv[rr][q+0]) + (1.0f - g[rr]) * uv[rr][q+0];
            yv.y = g[rr] * (xfv[rr][q+1] + xbv[rr][q+1]) + (1.0f - g[rr]) * uv[rr][q+1];
            yv.z = g[rr] * (xfv[rr][q+2] + xbv[rr][q+2]) + (1.0f - g[rr]) * uv[rr][q+2];
            yv.w = g[rr] * (xfv[rr][q+3] + xbv[rr][q+3]) + (1.0f - g[rr]) * uv[rr][q+3];
            *reinterpret_cast<float4*>(y + rb + e) = yv;
            p2[rr] += yv.x * wcv[q+0] + yv.y * wcv[q+1] + yv.z * wcv[q+2] + yv.w * wcv[q+3];
        }
    }
    #pragma unroll
    for (int off = 32; off >= 1; off >>= 1) {
        p2[0] += __shfl_xor(p2[0], off);
        p2[1] += __shfl_xor(p2[1], off);
    }
    if (lane == 0) {
        gout[r0]     = g[0];
        gout[r0 + 1] = g[1];
        fout[r0]     = 1.0f / (1.0f + __expf(-p2[0]));
        fout[r0 + 1] = 1.0f / (1.0f + __expf(-p2[1]));
    }
}

extern "C" void kernel_launch(void* const* d_in, const int* in_sizes, int n_in,
                              void* d_out, int out_size, void* d_ws, size_t ws_size,
                              hipStream_t stream) {
    const float* u   = (const float*)d_in[0];
    const float* WB  = (const float*)d_in[2];
    const float* WBf = (const float*)d_in[4];
    const float* w1  = (const float*)d_in[5];
    const float* w2  = (const float*)d_in[6];
    const float* bb  = (const float*)d_in[7];
    const float* Wc  = (const float*)d_in[8];

    char* ws = (char*)d_ws;
    bf16_t* u16  = (bf16_t*)(ws);                         //  64 MiB
    bf16_t* wcat = (bf16_t*)(ws + 67108864);              //   4 MiB
    bf16_t* xfw  = (bf16_t*)(ws + 71303168);              //  64 MiB
    bf16_t* xbw  = (bf16_t*)(ws + 138412032);             //  64 MiB

    float* y    = (float*)d_out;
    float* gout = y + (size_t)Mrows * Dd;
    float* fout = gout + Mrows;

    // fused casts: 8388608 u-groups + 524288 w-groups = 8912896 -> 34816 blocks
    k_prep<<<dim3(34816), dim3(256), 0, stream>>>(u, WB, WBf, u16, wcat);

    // (M/256)*(Ncat/256) = 128*8 = 1024 blocks, 512 threads
    k_gemm<<<dim3(1024), dim3(512), 0, stream>>>(u16, wcat, xfw, xbw);

    // two rows per wave, 8 rows per block
    k_epi<<<dim3(Mrows / 8), dim3(256), 0, stream>>>(u16, xfw, xbw, w1, w2, bb, Wc,
                                                     y, gout, fout);
}

// Round 9
// 428.199 us; speedup vs baseline: 1.0032x; 1.0032x over previous
//
#include <hip/hip_runtime.h>
#include <hip/hip_bf16.h>
#include <cstddef>

#define GLOBAL_AS __attribute__((address_space(1)))
#define LDS_AS __attribute__((address_space(3)))

typedef __bf16 bf16_t;
typedef __bf16 bf16x8 __attribute__((ext_vector_type(8)));
typedef __bf16 bf16x4 __attribute__((ext_vector_type(4)));
typedef float f32x4 __attribute__((ext_vector_type(4)));

static constexpr int Tseq  = 4096;
static constexpr int Dd    = 1024;
static constexpr int Mrows = 8 * 4096;            // 32768
static constexpr int UGRP  = 8388608;             // u float4-groups (32M/4)

// ---------------- fused cast: u -> u16, (WB,WBf) -> wcat --------------------
__global__ __launch_bounds__(256) void k_prep(const float* __restrict__ u,
                                              const float* __restrict__ WB,
                                              const float* __restrict__ WBf,
                                              bf16_t* __restrict__ u16,
                                              bf16_t* __restrict__ wcat) {
    const int i = blockIdx.x * 256 + threadIdx.x;
    if (i < UGRP) {
        float4 v = reinterpret_cast<const float4*>(u)[i];
        bf16x4 o;
        o[0] = (__bf16)v.x; o[1] = (__bf16)v.y; o[2] = (__bf16)v.z; o[3] = (__bf16)v.w;
        reinterpret_cast<bf16x4*>(u16)[i] = o;
    } else {
        const int j  = i - UGRP;                  // 0 .. 524287
        const int e4 = j * 4;
        const float* s = (e4 < 1024 * 1024) ? (WB + e4) : (WBf + (e4 - 1024 * 1024));
        float4 v = *reinterpret_cast<const float4*>(s);
        bf16x4 o;
        o[0] = (__bf16)v.x; o[1] = (__bf16)v.y; o[2] = (__bf16)v.z; o[3] = (__bf16)v.w;
        reinterpret_cast<bf16x4*>(wcat)[j] = o;
    }
}

// ---------------- 256x256x64 pipelined GEMM, 2 phases/K-tile ----------------
// Same sync schedule as R8 (passed 2x). NEW: all ds_read / global_load_lds
// addresses are loop-invariant base pointers + compile-time immediates.
// Legal because (rr&7) == (lane&7) for every fragment row, so the XOR-swizzle
// term is per-lane constant; mh/mi/nh/ni strides are +16384/+2048 adds.
__global__ __launch_bounds__(512, 2) void k_gemm(const bf16_t* __restrict__ A,
                                                 const bf16_t* __restrict__ Bt,
                                                 bf16_t* __restrict__ xf,
                                                 bf16_t* __restrict__ xb) {
    __shared__ __align__(16) char sm[131072];

    const int tid  = threadIdx.x;
    const int wid  = tid >> 6;
    const int lane = tid & 63;
    const int lane15 = lane & 15;
    const int g16  = (lane >> 4) * 16;     // byte offset of k-group {0,16,32,48}
    const int wmq  = wid >> 1;             // 0..3
    const int wnq  = wid & 1;              // 0..1

    // bijective XCD swizzle (nwg=1024, 8 XCDs)
    const int bid0 = blockIdx.x;
    const int swzb = (bid0 & 7) * 128 + (bid0 >> 3);
    const int bcol = swzb & 7;             // 8 col tiles of 256 over Ncat=2048
    const int brow = swzb >> 3;            // 128 row tiles of 256

    // ---- loop-invariant LDS read bases: [buf][kk] for A and B --------------
    const int sz = (lane & 7) << 4;                 // XOR-swizzle, lane-const
    const int c0 = g16 ^ sz;                        // kk=0 byte term
    const int c1 = (64 + g16) ^ sz;                 // kk=1 byte term
    const char* aB0k0 = sm + wmq * 4096 + lane15 * 128 + c0;
    const char* aB0k1 = sm + wmq * 4096 + lane15 * 128 + c1;
    const char* aB1k0 = aB0k0 + 65536;
    const char* aB1k1 = aB0k1 + 65536;
    const char* bB0k0 = sm + 32768 + wnq * 8192 + lane15 * 128 + c0;
    const char* bB0k1 = sm + 32768 + wnq * 8192 + lane15 * 128 + c1;
    const char* bB1k0 = bB0k0 + 65536;
    const char* bB1k1 = bB0k1 + 65536;

    // ---- staging: 8 precomputed global pointers, advanced +128 elems/pair --
    // dest byte L = tid*16 (+8192); logical = L ^ ((row&7)<<4)
    const int srow = tid >> 3;                        // 0..63
    const int scol = ((tid & 7) ^ (srow & 7)) * 8;    // elems
    const bf16_t* pA00 = A  + ((size_t)brow * 256 +   0 + srow) * 1024 + scol;
    const bf16_t* pA01 = A  + ((size_t)brow * 256 +  64 + srow) * 1024 + scol;
    const bf16_t* pA10 = A  + ((size_t)brow * 256 + 128 + srow) * 1024 + scol;
    const bf16_t* pA11 = A  + ((size_t)brow * 256 + 192 + srow) * 1024 + scol;
    const bf16_t* pB00 = Bt + ((size_t)bcol * 256 +   0 + srow) * 1024 + scol;
    const bf16_t* pB01 = Bt + ((size_t)bcol * 256 +  64 + srow) * 1024 + scol;
    const bf16_t* pB10 = Bt + ((size_t)bcol * 256 + 128 + srow) * 1024 + scol;
    const bf16_t* pB11 = Bt + ((size_t)bcol * 256 + 192 + srow) * 1024 + scol;

    char* const smw = sm + wid * 1024;     // per-wave stage dest (wave-uniform)

    f32x4 acc[2][2][2][4] = {};            // [mh][mi][nh][ni]
    bf16x8 afr[2][2][2];                   // [mh][mi][kk]
    bf16x8 bfr[4][2];                      // [ni][kk]

#define STG(BUF, ISA, H, P0, P1, IMME) do {                                    \
    char* _l = smw + (BUF) * 65536 + ((ISA) ? 0 : 32768) + (H) * 16384;        \
    __builtin_amdgcn_global_load_lds((const GLOBAL_AS void*)((P0) + (IMME)),   \
                                     (LDS_AS void*)_l, 16, 0, 0);              \
    __builtin_amdgcn_global_load_lds((const GLOBAL_AS void*)((P1) + (IMME)),   \
                                     (LDS_AS void*)(_l + 8192), 16, 0, 0);     \
} while (0)

#define RD_A_ALL(AK0, AK1) do {                                                \
    _Pragma("unroll") for (int mh = 0; mh < 2; ++mh)                           \
    _Pragma("unroll") for (int mi = 0; mi < 2; ++mi) {                         \
        afr[mh][mi][0] = *reinterpret_cast<const bf16x8*>((AK0) + mh * 16384 + mi * 2048); \
        afr[mh][mi][1] = *reinterpret_cast<const bf16x8*>((AK1) + mh * 16384 + mi * 2048); \
    } } while (0)

#define RD_B_H(BK0, BK1, NH) do {                                              \
    _Pragma("unroll") for (int ni = 0; ni < 4; ++ni) {                         \
        bfr[ni][0] = *reinterpret_cast<const bf16x8*>((BK0) + (NH) * 16384 + ni * 2048); \
        bfr[ni][1] = *reinterpret_cast<const bf16x8*>((BK1) + (NH) * 16384 + ni * 2048); \
    } } while (0)

#define MM(MH, NH) do {                                                        \
    _Pragma("unroll") for (int kk = 0; kk < 2; ++kk)                           \
    _Pragma("unroll") for (int mi = 0; mi < 2; ++mi)                           \
    _Pragma("unroll") for (int ni = 0; ni < 4; ++ni)                           \
      acc[MH][mi][NH][ni] = __builtin_amdgcn_mfma_f32_16x16x32_bf16(           \
          afr[MH][mi][kk], bfr[ni][kk], acc[MH][mi][NH][ni], 0, 0, 0);         \
} while (0)

#define BARM() asm volatile("s_barrier" ::: "memory")

// One K-tile, buffer BUF (literal 0/1), prefetch PF (literal), stage imm IMME.
// Schedule identical to R8: [RD_A,RD_B0 | stage 3 halves | bar | 32 MFMA |
// vmcnt(6)/0 | bar]  [RD_B1 | stage B1' | bar | 32 MFMA | vmcnt(2) | bar]
#define TILE(BUF, AK0, AK1, BK0, BK1, PF, IMME) do {                           \
    RD_A_ALL(AK0, AK1);                                                        \
    RD_B_H(BK0, BK1, 0);                                                       \
    if (PF) { STG(BUF ^ 1, 1, 0, pA00, pA01, IMME);                            \
              STG(BUF ^ 1, 0, 0, pB00, pB01, IMME);                            \
              STG(BUF ^ 1, 1, 1, pA10, pA11, IMME); }                          \
    __builtin_amdgcn_s_barrier();                                              \
    __builtin_amdgcn_s_setprio(1);                                             \
    MM(0, 0); MM(1, 0);                                                        \
    __builtin_amdgcn_s_setprio(0);                                             \
    if (PF) { asm volatile("s_waitcnt vmcnt(6)" ::: "memory"); }               \
    else    { asm volatile("s_waitcnt vmcnt(0)" ::: "memory"); }               \
    BARM();                                                                    \
    RD_B_H(BK0, BK1, 1);                                                       \
    if (PF) STG(BUF ^ 1, 0, 1, pB10, pB11, IMME);                              \
    __builtin_amdgcn_s_barrier();                                              \
    __builtin_amdgcn_s_setprio(1);                                             \
    MM(1, 1); MM(0, 1);                                                        \
    __builtin_amdgcn_s_setprio(0);                                             \
    if (PF) { asm volatile("s_waitcnt vmcnt(2)" ::: "memory"); }               \
    BARM();                                                                    \
} while (0)

    // prologue: stage tile 0 halves A0,B0,A1,B1 at k-offset 0
    STG(0, 1, 0, pA00, pA01, 0);
    STG(0, 0, 0, pB00, pB01, 0);
    STG(0, 1, 1, pA10, pA11, 0);
    STG(0, 0, 1, pB10, pB11, 0);
    asm volatile("s_waitcnt vmcnt(2)" ::: "memory");   // A0,B0,A1 done
    BARM();

    // 16 K-tiles as 8 pairs; stage imm: tile 2s stages k=(2s+1)*64 -> +64;
    // tile 2s+1 stages k=(2s+2)*64 -> +128; then advance all ptrs +128 elems.
    for (int s = 0; s < 7; ++s) {
        TILE(0, aB0k0, aB0k1, bB0k0, bB0k1, 1, 64);
        TILE(1, aB1k0, aB1k1, bB1k0, bB1k1, 1, 128);
        pA00 += 128; pA01 += 128; pA10 += 128; pA11 += 128;
        pB00 += 128; pB01 += 128; pB10 += 128; pB11 += 128;
    }
    TILE(0, aB0k0, aB0k1, bB0k0, bB0k1, 1, 64);   // t=14, stages tile 15
    TILE(1, aB1k0, aB1k1, bB1k0, bB1k1, 0, 0);    // t=15, no prefetch

    // C-write. n<1024 -> xf[m,n]; n>=1024 -> xb[m-1,n-1024] (skip m==0).
    const bool isF  = bcol < 4;           // block-uniform
    const int rbase = brow * 256 + wmq * 32 + (lane >> 4) * 4;
    const int cb0   = bcol * 256 + wnq * 64 + lane15;
    #pragma unroll
    for (int mh = 0; mh < 2; ++mh)
    #pragma unroll
    for (int mi = 0; mi < 2; ++mi)
    #pragma unroll
    for (int j = 0; j < 4; ++j) {
        const int r = rbase + mh * 128 + mi * 16 + j;
        #pragma unroll
        for (int nh = 0; nh < 2; ++nh)
        #pragma unroll
        for (int ni = 0; ni < 4; ++ni) {
            const int c = cb0 + nh * 128 + ni * 16;
            const __bf16 v = (__bf16)acc[mh][mi][nh][ni][j];
            if (isF)         xf[(size_t)r * 1024 + c] = v;
            else if (r >= 1) xb[(size_t)(r - 1) * 1024 + (c - 1024)] = v;
        }
    }
#undef STG
#undef RD_A_ALL
#undef RD_B_H
#undef MM
#undef TILE
#undef BARM
}

// ---------------- epilogue: TWO rows per wave (ILP), bf16 u, float4 weights --
__global__ __launch_bounds__(256) void k_epi(const bf16_t* __restrict__ u16,
                                             const bf16_t* __restrict__ xf,
                                             const bf16_t* __restrict__ xb,
                                             const float* __restrict__ w1,
                                             const float* __restrict__ w2,
                                             const float* __restrict__ bb,
                                             const float* __restrict__ Wc,
                                             float* __restrict__ y,
                                             float* __restrict__ gout,
                                             float* __restrict__ fout) {
    const int lane = threadIdx.x & 63;
    const int r0   = blockIdx.x * 8 + (threadIdx.x >> 6) * 2;   // rows r0, r0+1

    // issue all 12 row loads first
    bf16x8 u8[2][2], f8[2][2], b8[2][2];
    #pragma unroll
    for (int rr = 0; rr < 2; ++rr) {
        const size_t rb = (size_t)(r0 + rr) * Dd;
        #pragma unroll
        for (int j = 0; j < 2; ++j) {
            const int e = j * 512 + lane * 8;
            u8[rr][j] = *reinterpret_cast<const bf16x8*>(u16 + rb + e);
            f8[rr][j] = *reinterpret_cast<const bf16x8*>(xf + rb + e);
            b8[rr][j] = *reinterpret_cast<const bf16x8*>(xb + rb + e);
        }
    }
    // weights as float4 (12 loads total)
    float w1v[16], w2v[16], wcv[16];
    #pragma unroll
    for (int j = 0; j < 2; ++j) {
        const int q4 = j * 128 + lane * 2;      // float4 index of e = j*512+lane*8
        #pragma unroll
        for (int h = 0; h < 2; ++h) {
            const float4 a = reinterpret_cast<const float4*>(w1)[q4 + h];
            const float4 c = reinterpret_cast<const float4*>(w2)[q4 + h];
            const float4 w = reinterpret_cast<const float4*>(Wc)[q4 + h];
            const int o = j * 8 + h * 4;
            w1v[o+0] = a.x; w1v[o+1] = a.y; w1v[o+2] = a.z; w1v[o+3] = a.w;
            w2v[o+0] = c.x; w2v[o+1] = c.y; w2v[o+2] = c.z; w2v[o+3] = c.w;
            wcv[o+0] = w.x; wcv[o+1] = w.y; wcv[o+2] = w.z; wcv[o+3] = w.w;
        }
    }

    float uv[2][16], xfv[2][16], xbv[2][16];
    #pragma unroll
    for (int rr = 0; rr < 2; ++rr) {
        const int t = (r0 + rr) & (Tseq - 1);
        #pragma unroll
        for (int j = 0; j < 2; ++j) {
            #pragma unroll
            for (int i = 0; i < 8; ++i) {
                uv[rr][j*8+i]  = (float)u8[rr][j][i];
                xfv[rr][j*8+i] = (float)f8[rr][j][i];
                xbv[rr][j*8+i] = (float)b8[rr][j][i];
            }
        }
        if (t == 0) {
            #pragma unroll
            for (int i = 0; i < 16; ++i) xfv[rr][i] = uv[rr][i];
        }
        if (t == Tseq - 1) {
            #pragma unroll
            for (int i = 0; i < 16; ++i) xbv[rr][i] = uv[rr][i];
        }
    }

    float part[2] = {0.0f, 0.0f};
    #pragma unroll
    for (int rr = 0; rr < 2; ++rr)
        #pragma unroll
        for (int i = 0; i < 16; ++i)
            part[rr] += xfv[rr][i] * w1v[i] + xbv[rr][i] * w2v[i];
    #pragma unroll
    for (int off = 32; off >= 1; off >>= 1) {
        part[0] += __shfl_xor(part[0], off);
        part[1] += __shfl_xor(part[1], off);
    }
    const float bias = bb[0];
    float g[2];
    g[0] = 1.0f / (1.0f + __expf(-(part[0] + bias)));
    g[1] = 1.0f / (1.0f + __expf(-(part[1] + bias)));

    float p2[2] = {0.0f, 0.0f};
    #pragma unroll
    for (int rr = 0; rr < 2; ++rr) {
        const size_t rb = (size_t)(r0 + rr) * Dd;
        #pragma unroll
        for (int j = 0; j < 4; ++j) {          // 4 x float4 stores per row
            float4 yv;
            const int e = (j >> 1) * 512 + lane * 8 + (j & 1) * 4;
            const int q = (j >> 1) * 8 + (j & 1) * 4;
            yv.x = g[rr] * (xfv[rr][q+0] + xbv[rr][q+0]) + (1.0f - g[rr]) * uv[rr][q+0];
            yv.y = g[rr] * (xfv[rr][q+1] + xbv[rr][q+1]) + (1.0f - g[rr]) * uv[rr][q+1];
            yv.z = g[rr] * (xfv[rr][q+2] + xbv[rr][q+2]) + (1.0f - g[rr]) * uv[rr][q+2];
            yv.w = g[rr] * (xfv[rr][q+3] + xbv[rr][q+3]) + (1.0f - g[rr]) * uv[rr][q+3];
            *reinterpret_cast<float4*>(y + rb + e) = yv;
            p2[rr] += yv.x * wcv[q+0] + yv.y * wcv[q+1] + yv.z * wcv[q+2] + yv.w * wcv[q+3];
        }
    }
    #pragma unroll
    for (int off = 32; off >= 1; off >>= 1) {
        p2[0] += __shfl_xor(p2[0], off);
        p2[1] += __shfl_xor(p2[1], off);
    }
    if (lane == 0) {
        gout[r0]     = g[0];
        gout[r0 + 1] = g[1];
        fout[r0]     = 1.0f / (1.0f + __expf(-p2[0]));
        fout[r0 + 1] = 1.0f / (1.0f + __expf(-p2[1]));
    }
}

extern "C" void kernel_launch(void* const* d_in, const int* in_sizes, int n_in,
                              void* d_out, int out_size, void* d_ws, size_t ws_size,
                              hipStream_t stream) {
    const float* u   = (const float*)d_in[0];
    const float* WB  = (const float*)d_in[2];
    const float* WBf = (const float*)d_in[4];
    const float* w1  = (const float*)d_in[5];
    const float* w2  = (const float*)d_in[6];
    const float* bb  = (const float*)d_in[7];
    const float* Wc  = (const float*)d_in[8];

    char* ws = (char*)d_ws;
    bf16_t* u16  = (bf16_t*)(ws);                         //  64 MiB
    bf16_t* wcat = (bf16_t*)(ws + 67108864);              //   4 MiB
    bf16_t* xfw  = (bf16_t*)(ws + 71303168);              //  64 MiB
    bf16_t* xbw  = (bf16_t*)(ws + 138412032);             //  64 MiB

    float* y    = (float*)d_out;
    float* gout = y + (size_t)Mrows * Dd;
    float* fout = gout + Mrows;

    // fused casts: 8388608 u-groups + 524288 w-groups = 8912896 -> 34816 blocks
    k_prep<<<dim3(34816), dim3(256), 0, stream>>>(u, WB, WBf, u16, wcat);

    // (M/256)*(Ncat/256) = 128*8 = 1024 blocks, 512 threads
    k_gemm<<<dim3(1024), dim3(512), 0, stream>>>(u16, wcat, xfw, xbw);

    // two rows per wave, 8 rows per block
    k_epi<<<dim3(Mrows / 8), dim3(256), 0, stream>>>(u16, xfw, xbw, w1, w2, bb, Wc,
                                                     y, gout, fout);
}